// Round 15
// baseline (322.610 us; speedup 1.0000x reference)
//
#include <hip/hip_runtime.h>
#include <hip/hip_bf16.h>
#include <hip/hip_fp16.h>

typedef __attribute__((ext_vector_type(8))) short short8;
typedef __attribute__((ext_vector_type(8))) _Float16 f16x8;
typedef __attribute__((ext_vector_type(4))) float f32x4;

// ================= CSR build: two-pass counting sort by dst-bin =================
#define EPB 16384

__global__ __launch_bounds__(256) void k_lhist(const int* __restrict__ dst, int* __restrict__ histT,
                                               int nE, int nblk, int nbins) {
  __shared__ int c[1024];
  int tid = threadIdx.x;
  for (int i = tid; i < nbins; i += 256) c[i] = 0;
  __syncthreads();
  int blk = blockIdx.x;
  int e0 = blk * EPB;
  int e1 = min(nE, e0 + EPB);
  if (e1 - e0 == EPB) {
#pragma unroll
    for (int it = 0; it < EPB / 1024; ++it) {
      int4 d = *(const int4*)(dst + e0 + it * 1024 + tid * 4);
      atomicAdd(&c[d.x >> 7], 1);
      atomicAdd(&c[d.y >> 7], 1);
      atomicAdd(&c[d.z >> 7], 1);
      atomicAdd(&c[d.w >> 7], 1);
    }
  } else {
    for (int i = e0 + tid; i < e1; i += 256) atomicAdd(&c[dst[i] >> 7], 1);
  }
  __syncthreads();
  for (int i = tid; i < nbins; i += 256) histT[i * nblk + blk] = c[i];
}

__global__ __launch_bounds__(256) void k_lscatter(
    const int* __restrict__ src, const int* __restrict__ dst, const int* __restrict__ subPtr,
    int* __restrict__ binned, int nE, int nblk, int nbins) {
  __shared__ int cur[1024];
  int tid = threadIdx.x;
  int blk = blockIdx.x;
  for (int i = tid; i < nbins; i += 256) cur[i] = subPtr[i * nblk + blk];
  __syncthreads();
  int e0 = blk * EPB;
  int e1 = min(nE, e0 + EPB);
  if (e1 - e0 == EPB) {
#pragma unroll
    for (int it = 0; it < EPB / 1024; ++it) {
      int base = e0 + it * 1024 + tid * 4;
      int4 s = *(const int4*)(src + base);
      int4 d = *(const int4*)(dst + base);
      int p0 = atomicAdd(&cur[d.x >> 7], 1);
      int p1 = atomicAdd(&cur[d.y >> 7], 1);
      int p2 = atomicAdd(&cur[d.z >> 7], 1);
      int p3 = atomicAdd(&cur[d.w >> 7], 1);
      binned[p0] = s.x | ((d.x & 127) << 20);
      binned[p1] = s.y | ((d.y & 127) << 20);
      binned[p2] = s.z | ((d.z & 127) << 20);
      binned[p3] = s.w | ((d.w & 127) << 20);
    }
  } else {
    for (int i = e0 + tid; i < e1; i += 256) {
      int d = dst[i];
      int pos = atomicAdd(&cur[d >> 7], 1);
      binned[pos] = src[i] | ((d & 127) << 20);
    }
  }
}

__global__ __launch_bounds__(256) void k_bin_cnt(
    const int* __restrict__ binned, const int* __restrict__ subPtr,
    int* __restrict__ cnt, int nE, int nblk, int nbins, int n) {
  __shared__ int c128[128];
  int b = blockIdx.x;
  int tid = threadIdx.x;
  if (tid < 128) c128[tid] = 0;
  __syncthreads();
  int s0 = subPtr[b * nblk];
  int s1 = (b + 1 < nbins) ? subPtr[(b + 1) * nblk] : nE;
  for (int i = s0 + tid; i < s1; i += 256)
    atomicAdd(&c128[(binned[i] >> 20) & 127], 1);
  __syncthreads();
  if (tid < 128) {
    int idx = (b << 7) + tid;
    if (idx < n) cnt[idx] = c128[tid];
  }
}

__global__ __launch_bounds__(256) void k_bin_place(
    const int* __restrict__ binned, const int* __restrict__ subPtr,
    const int* __restrict__ rowptr, int* __restrict__ col, int nE, int nblk, int nbins, int n) {
  __shared__ int cur128[128];
  int b = blockIdx.x;
  int tid = threadIdx.x;
  if (tid < 128) {
    int idx = (b << 7) + tid;
    cur128[tid] = (idx < n) ? rowptr[idx] : 0;
  }
  __syncthreads();
  int s0 = subPtr[b * nblk];
  int s1 = (b + 1 < nbins) ? subPtr[(b + 1) * nblk] : nE;
  for (int i = s0 + tid; i < s1; i += 256) {
    int e = binned[i];
    int pos = atomicAdd(&cur128[(e >> 20) & 127], 1);
    col[pos] = e & 0xFFFFF;
  }
}

// ---- 3-phase exclusive scan ----

__global__ void k_blocksum(const int* __restrict__ cnt, int* __restrict__ bsum, int n) {
  __shared__ int red[256];
  int tid = threadIdx.x;
  int base = blockIdx.x * 1024 + tid * 4;
  int s = 0;
#pragma unroll
  for (int i = 0; i < 4; i++) { int idx = base + i; if (idx < n) s += cnt[idx]; }
  red[tid] = s;
  __syncthreads();
  for (int off = 128; off > 0; off >>= 1) {
    if (tid < off) red[tid] += red[tid + off];
    __syncthreads();
  }
  if (tid == 0) bsum[blockIdx.x] = red[0];
}

__global__ void k_scan_bsum(int* __restrict__ bsum, int nb) {
  __shared__ int s[128];
  int tid = threadIdx.x;
  int v = (tid < nb) ? bsum[tid] : 0;
  s[tid] = v;
  __syncthreads();
  for (int off = 1; off < 128; off <<= 1) {
    int t = (tid >= off) ? s[tid - off] : 0;
    __syncthreads();
    s[tid] += t;
    __syncthreads();
  }
  if (tid < nb) bsum[tid] = s[tid] - v;  // exclusive
}

__global__ void k_scan_final(const int* __restrict__ cnt, const int* __restrict__ bsum,
                             int* __restrict__ rowptr, float* __restrict__ dinv, int n) {
  __shared__ int tsum[256];
  int tid = threadIdx.x;
  int base = blockIdx.x * 1024 + tid * 4;
  int v[4]; int s = 0;
#pragma unroll
  for (int i = 0; i < 4; i++) { v[i] = (base + i < n) ? cnt[base + i] : 0; s += v[i]; }
  tsum[tid] = s;
  __syncthreads();
  for (int off = 1; off < 256; off <<= 1) {
    int t = (tid >= off) ? tsum[tid - off] : 0;
    __syncthreads();
    tsum[tid] += t;
    __syncthreads();
  }
  int run = bsum[blockIdx.x] + tsum[tid] - s;
#pragma unroll
  for (int i = 0; i < 4; i++) {
    int idx = base + i;
    if (idx < n) {
      rowptr[idx] = run;
      if (dinv) dinv[idx] = rsqrtf((float)(v[i] + 1));  // +1 self-loop
      run += v[i];
    }
  }
}

// ---- weight prep: fp16 + transpose; fuse Wmu|Wls, bmu|bls ----

__global__ void k_prep_w(const float* __restrict__ W1,
                         const float* __restrict__ Wmu, const float* __restrict__ Wls,
                         const float* __restrict__ bmu, const float* __restrict__ bls,
                         __half* __restrict__ W1T, __half* __restrict__ WcT,
                         float* __restrict__ bcat) {
  int i = blockIdx.x * blockDim.x + threadIdx.x;
  if (i < 128 * 256) {                     // W1T [n][k]
    int n = i >> 8, k = i & 255;
    W1T[i] = __float2half(W1[k * 128 + n]);
  } else if (i < 2 * 128 * 256) {          // WcT [n][k]
    int j = i - 128 * 256;
    int n = j >> 7, k = j & 127;
    float f = (n < 128) ? Wmu[k * 128 + n] : Wls[k * 128 + (n - 128)];
    WcT[j] = __float2half(f);
  } else if (i < 2 * 128 * 256 + 256) {    // bcat
    int n = i - 2 * 128 * 256;
    bcat[n] = (n < 128) ? bmu[n] : bls[n - 128];
  }
}

// ---------------- GEMM1, TLP-style: h0 = fp16(x) @ W1T^T ----------------
// Block = 16 rows, grid N/16 (~6250 blocks, 25K waves — SpMM-like TLP).
// Phase 1: coalesced f32 load -> fp16 -> padded LDS (stride 33 chunks).
// Phase 2: 16 MFMAs/wave, a from LDS, b streamed from L2-resident W1T (64KB).
// Phase 3: LDS transpose -> fully coalesced 16B h0 stores.

__global__ __launch_bounds__(256) void k_gemm1(
    const float* __restrict__ x, const __half* __restrict__ W1T,
    __half* __restrict__ h0, int n) {
  __shared__ _Float16 xt[16 * 264];   // 16 rows x 256 halves, stride 264 (33 16B-chunks)
  __shared__ _Float16 ht[16 * 136];   // 16 rows x 128 halves, stride 136 (17 chunks)
  const int tid = threadIdx.x;

  // ---- phase 1 ----
  {
    const int row = tid >> 4;
    const int seg = tid & 15;          // 16-float segment of the 256-col row
    const int gnode = blockIdx.x * 16 + row;
    f16x8 v0 = (f16x8){0, 0, 0, 0, 0, 0, 0, 0}, v1 = v0;
    if (gnode < n) {
      const float* ap = x + (size_t)gnode * 256 + seg * 16;
      float4 f0 = *(const float4*)(ap);
      float4 f1 = *(const float4*)(ap + 4);
      float4 f2 = *(const float4*)(ap + 8);
      float4 f3 = *(const float4*)(ap + 12);
      v0[0]=(_Float16)f0.x; v0[1]=(_Float16)f0.y; v0[2]=(_Float16)f0.z; v0[3]=(_Float16)f0.w;
      v0[4]=(_Float16)f1.x; v0[5]=(_Float16)f1.y; v0[6]=(_Float16)f1.z; v0[7]=(_Float16)f1.w;
      v1[0]=(_Float16)f2.x; v1[1]=(_Float16)f2.y; v1[2]=(_Float16)f2.z; v1[3]=(_Float16)f2.w;
      v1[4]=(_Float16)f3.x; v1[5]=(_Float16)f3.y; v1[6]=(_Float16)f3.z; v1[7]=(_Float16)f3.w;
    }
    *(f16x8*)&xt[row * 264 + seg * 16]     = v0;
    *(f16x8*)&xt[row * 264 + seg * 16 + 8] = v1;
  }
  __syncthreads();

  // ---- phase 2: MFMA 16 rows x 128 cols, K=256 ----
  const int lane = tid & 63;
  const int w = tid >> 6;
  const int lr = lane & 15;
  const int lk = lane >> 4;

  f16x8 a[8];
#pragma unroll
  for (int ks = 0; ks < 8; ks++)
    a[ks] = *(const f16x8*)&xt[lr * 264 + (ks * 4 + lk) * 8];

#pragma unroll
  for (int ct = 0; ct < 2; ct++) {
    const int coln = w * 32 + ct * 16 + lr;
    f32x4 acc = (f32x4){0.f, 0.f, 0.f, 0.f};
    const _Float16* wrow = (const _Float16*)W1T + (size_t)coln * 256 + lk * 8;
#pragma unroll
    for (int ks = 0; ks < 8; ks++) {
      f16x8 b = *(const f16x8*)(wrow + ks * 32);
      acc = __builtin_amdgcn_mfma_f32_16x16x32_f16(a[ks], b, acc, 0, 0, 0);
    }
#pragma unroll
    for (int r = 0; r < 4; r++)
      ht[(lk * 4 + r) * 136 + coln] = (_Float16)acc[r];
  }
  __syncthreads();

  // ---- phase 3: coalesced store ----
  {
    const int row = tid >> 4;
    const int chunk = tid & 15;        // 128 halves = 16 chunks of 8
    const int gnode = blockIdx.x * 16 + row;
    if (gnode < n)
      *(f16x8*)(h0 + (size_t)gnode * 128 + chunk * 8) =
          *(const f16x8*)&ht[row * 136 + chunk * 8];
  }
}

// ---------------- pull-based SpMM (fp16 rows, on-the-fly norm) ----------------

__global__ __launch_bounds__(256) void k_spmm_h(
    const __half* __restrict__ in, const int* __restrict__ rowptr,
    const int* __restrict__ cnt, const int* __restrict__ col,
    const float* __restrict__ dinv,
    const float* __restrict__ bias, __half* __restrict__ out,
    int n, int use_bias, int relu_out) {
  int node = blockIdx.x * 4 + (threadIdx.x >> 6);
  if (node >= n) return;
  int lane = threadIdx.x & 63;

  const __half2* inp = (const __half2*)in;
  float di = dinv[node];
  float2 v = __half22float2(inp[(size_t)node * 64 + lane]);
  float accx = di * v.x;
  float accy = di * v.y;

  int beg = rowptr[node];
  int m = cnt[node];
  int i = 0;
  for (; i + 8 <= m; i += 8) {
    int c[8];
#pragma unroll
    for (int j = 0; j < 8; j++) c[j] = col[beg + i + j];
    float e[8];
#pragma unroll
    for (int j = 0; j < 8; j++) e[j] = dinv[c[j]];
    float2 u[8];
#pragma unroll
    for (int j = 0; j < 8; j++) u[j] = __half22float2(inp[(size_t)c[j] * 64 + lane]);
#pragma unroll
    for (int j = 0; j < 8; j++) { accx += e[j] * u[j].x; accy += e[j] * u[j].y; }
  }
  if (i < m) {
    int c[8];
#pragma unroll
    for (int j = 0; j < 8; j++) c[j] = col[(i + j < m) ? (beg + i + j) : beg];
    float e[8];
#pragma unroll
    for (int j = 0; j < 8; j++) e[j] = (i + j < m) ? dinv[c[j]] : 0.f;
    float2 u[8];
#pragma unroll
    for (int j = 0; j < 8; j++) u[j] = __half22float2(inp[(size_t)c[j] * 64 + lane]);
#pragma unroll
    for (int j = 0; j < 8; j++) { accx += e[j] * u[j].x; accy += e[j] * u[j].y; }
  }
  accx *= di;
  accy *= di;
  if (use_bias) {
    accx += bias[2 * lane];
    accy += bias[2 * lane + 1];
  }
  if (relu_out) {
    accx = fmaxf(accx, 0.f);
    accy = fmaxf(accy, 0.f);
  }
  ((__half2*)(out + (size_t)node * 128))[lane] = __floats2half2_rn(accx, accy);
}

// ---------------- fused SpMM2 + GEMM2: [mu|ls] = (A h) @ [Wmu|Wls] + b ----------------
// Block = 16 nodes, 4 waves x 4 nodes. Phase 1: gather g-rows -> swizzled LDS (4KB).
// Phase 2: 16x256 = gt[16x128] @ WcT^T via MFMA. g never touches global memory.

__global__ __launch_bounds__(256) void k_spmm_gemm(
    const __half* __restrict__ in, const int* __restrict__ rowptr,
    const int* __restrict__ cnt, const int* __restrict__ col,
    const float* __restrict__ dinv,
    const __half* __restrict__ WcT, const float* __restrict__ bcat,
    float* __restrict__ out0, float* __restrict__ out1, int n) {
  __shared__ _Float16 gt[16 * 128];   // 16 rows x 256B, 16B-chunk XOR-swizzled by row
  const int tid = threadIdx.x;
  const int lane = tid & 63;
  const int w = tid >> 6;
  const __half2* inp = (const __half2*)in;

  // ---- phase 1: 4 g-rows per wave ----
  for (int q = 0; q < 4; q++) {
    int li = w * 4 + q;
    int node = blockIdx.x * 16 + li;
    float accx = 0.f, accy = 0.f;
    if (node < n) {
      float di = dinv[node];
      float2 v = __half22float2(inp[(size_t)node * 64 + lane]);
      accx = di * v.x;
      accy = di * v.y;
      int beg = rowptr[node];
      int m = cnt[node];
      int i = 0;
      for (; i + 8 <= m; i += 8) {
        int c[8];
#pragma unroll
        for (int j = 0; j < 8; j++) c[j] = col[beg + i + j];
        float e[8];
#pragma unroll
        for (int j = 0; j < 8; j++) e[j] = dinv[c[j]];
        float2 u[8];
#pragma unroll
        for (int j = 0; j < 8; j++) u[j] = __half22float2(inp[(size_t)c[j] * 64 + lane]);
#pragma unroll
        for (int j = 0; j < 8; j++) { accx += e[j] * u[j].x; accy += e[j] * u[j].y; }
      }
      if (i < m) {
        int c[8];
#pragma unroll
        for (int j = 0; j < 8; j++) c[j] = col[(i + j < m) ? (beg + i + j) : beg];
        float e[8];
#pragma unroll
        for (int j = 0; j < 8; j++) e[j] = (i + j < m) ? dinv[c[j]] : 0.f;
        float2 u[8];
#pragma unroll
        for (int j = 0; j < 8; j++) u[j] = __half22float2(inp[(size_t)c[j] * 64 + lane]);
#pragma unroll
        for (int j = 0; j < 8; j++) { accx += e[j] * u[j].x; accy += e[j] * u[j].y; }
      }
      accx *= di;
      accy *= di;
    }
    int slot = (lane >> 2) ^ (li & 7);
    *(__half2*)((char*)gt + li * 256 + slot * 16 + (lane & 3) * 4) =
        __floats2half2_rn(accx, accy);
  }
  __syncthreads();

  // ---- phase 2: MFMA 16 rows x 256 cols ----
  const int lr = lane & 15;
  const int lk = lane >> 4;
  f16x8 a[4];
#pragma unroll
  for (int ks = 0; ks < 4; ks++) {
    int slot = (ks * 4 + lk) ^ (lr & 7);
    a[ks] = *(const f16x8*)((const char*)gt + lr * 256 + slot * 16);
  }
#pragma unroll
  for (int ct = 0; ct < 4; ct++) {
    int colg = (w * 4 + ct) * 16 + lr;    // 0..255
    f32x4 acc = (f32x4){0.f, 0.f, 0.f, 0.f};
#pragma unroll
    for (int ks = 0; ks < 4; ks++) {
      f16x8 b = *(const f16x8*)((const _Float16*)WcT + (size_t)colg * 128 + ks * 32 + lk * 8);
      acc = __builtin_amdgcn_mfma_f32_16x16x32_f16(a[ks], b, acc, 0, 0, 0);
    }
    float badd = bcat[colg];
    float* dst = out0;
    int c = colg;
    if (c >= 128) { dst = out1; c -= 128; }
#pragma unroll
    for (int r = 0; r < 4; r++) {
      int node = blockIdx.x * 16 + lk * 4 + r;
      if (node < n) dst[(size_t)node * 128 + c] = acc[r] + badd;
    }
  }
}

// ---------------- launch ----------------

extern "C" void kernel_launch(void* const* d_in, const int* in_sizes, int n_in,
                              void* d_out, int out_size, void* d_ws, size_t ws_size,
                              hipStream_t stream) {
  const float* x   = (const float*)d_in[0];
  const int*   ei  = (const int*)d_in[1];
  const float* W1  = (const float*)d_in[2];
  const float* b1  = (const float*)d_in[3];
  const float* Wmu = (const float*)d_in[4];
  const float* bmu = (const float*)d_in[5];
  const float* Wls = (const float*)d_in[6];
  const float* bls = (const float*)d_in[7];

  int N = in_sizes[0] / 256;
  int E = in_sizes[1] / 2;
  const int* src = ei;
  const int* dst = ei + E;

  int NBINS = (N + 127) >> 7;
  int NBLK  = (E + EPB - 1) / EPB;
  int NS    = NBINS * NBLK;

  char* ws = (char*)d_ws;
  size_t o = 0;
  auto alloc = [&](size_t b) { size_t c = o; o = (o + b + 511) & ~(size_t)511; return c; };
  int*   cnt     = (int*)(ws + alloc((size_t)N * 4));
  int*   rowptr  = (int*)(ws + alloc((size_t)N * 4));
  float* dinv    = (float*)(ws + alloc((size_t)N * 4));
  int*   bsum    = (int*)(ws + alloc(512));
  int*   histT   = (int*)(ws + alloc((size_t)NS * 4));
  int*   subPtr  = (int*)(ws + alloc((size_t)NS * 4));
  int*   col     = (int*)(ws + alloc((size_t)E * 4));
  int*   binned  = (int*)(ws + alloc((size_t)E * 4));
  __half* W1T  = (__half*)(ws + alloc(128 * 256 * 2));
  __half* WcT  = (__half*)(ws + alloc(256 * 128 * 2));
  float*  bcat = (float*)(ws + alloc(256 * 4));
  __half* h0   = (__half*)(ws + alloc((size_t)N * 128 * 2));  // GEMM1 out
  __half* hBuf = (__half*)(ws + alloc((size_t)N * 128 * 2));  // h (relu'd)

  float* outMu = (float*)d_out;
  float* outLs = outMu + (size_t)N * 128;

  int nbScanN = (N + 1023) / 1024;
  int nbScanS = (NS + 1023) / 1024;

  // ---- CSR build (counting sort by bin, block-private windows) ----
  k_lhist<<<NBLK, 256, 0, stream>>>(dst, histT, E, NBLK, NBINS);
  k_blocksum<<<nbScanS, 256, 0, stream>>>(histT, bsum, NS);
  k_scan_bsum<<<1, 128, 0, stream>>>(bsum, nbScanS);
  k_scan_final<<<nbScanS, 256, 0, stream>>>(histT, bsum, subPtr, nullptr, NS);
  k_lscatter<<<NBLK, 256, 0, stream>>>(src, dst, subPtr, binned, E, NBLK, NBINS);
  k_bin_cnt<<<NBINS, 256, 0, stream>>>(binned, subPtr, cnt, E, NBLK, NBINS, N);
  k_blocksum<<<nbScanN, 256, 0, stream>>>(cnt, bsum, N);
  k_scan_bsum<<<1, 128, 0, stream>>>(bsum, nbScanN);
  k_scan_final<<<nbScanN, 256, 0, stream>>>(cnt, bsum, rowptr, dinv, N);
  k_bin_place<<<NBINS, 256, 0, stream>>>(binned, subPtr, rowptr, col, E, NBLK, NBINS, N);

  // ---- weights ----
  k_prep_w<<<(2 * 128 * 256 + 256 + 255) / 256, 256, 0, stream>>>(
      W1, Wmu, Wls, bmu, bls, W1T, WcT, bcat);

  // h0 = x @ W1                 [N,128] fp16  (TLP-style, 16 rows/block)
  k_gemm1<<<(N + 15) / 16, 256, 0, stream>>>(x, W1T, h0, N);
  // h = relu(A h0 + b1)         [N,128] fp16
  k_spmm_h<<<(N + 3) / 4, 256, 0, stream>>>(h0, rowptr, cnt, col, dinv, b1, hBuf, N, 1, 1);
  // [mu|ls] = (A h) @ [Wmu|Wls] + [bmu|bls]   fused: g stays in LDS
  k_spmm_gemm<<<(N + 15) / 16, 256, 0, stream>>>(
      hBuf, rowptr, cnt, col, dinv, WcT, bcat, outMu, outLs, N);
}

// Round 16
// 300.607 us; speedup vs baseline: 1.0732x; 1.0732x over previous
//
#include <hip/hip_runtime.h>
#include <hip/hip_bf16.h>
#include <hip/hip_fp16.h>

typedef __attribute__((ext_vector_type(8))) short short8;
typedef __attribute__((ext_vector_type(8))) _Float16 f16x8;
typedef __attribute__((ext_vector_type(4))) float f32x4;

// ================= CSR build: two-pass counting sort by dst-bin =================
#define EPB 16384

__global__ __launch_bounds__(256) void k_lhist(const int* __restrict__ dst, int* __restrict__ histT,
                                               int nE, int nblk, int nbins) {
  __shared__ int c[1024];
  int tid = threadIdx.x;
  for (int i = tid; i < nbins; i += 256) c[i] = 0;
  __syncthreads();
  int blk = blockIdx.x;
  int e0 = blk * EPB;
  int e1 = min(nE, e0 + EPB);
  if (e1 - e0 == EPB) {
#pragma unroll
    for (int it = 0; it < EPB / 1024; ++it) {
      int4 d = *(const int4*)(dst + e0 + it * 1024 + tid * 4);
      atomicAdd(&c[d.x >> 7], 1);
      atomicAdd(&c[d.y >> 7], 1);
      atomicAdd(&c[d.z >> 7], 1);
      atomicAdd(&c[d.w >> 7], 1);
    }
  } else {
    for (int i = e0 + tid; i < e1; i += 256) atomicAdd(&c[dst[i] >> 7], 1);
  }
  __syncthreads();
  for (int i = tid; i < nbins; i += 256) histT[i * nblk + blk] = c[i];
}

__global__ __launch_bounds__(256) void k_lscatter(
    const int* __restrict__ src, const int* __restrict__ dst, const int* __restrict__ subPtr,
    int* __restrict__ binned, int nE, int nblk, int nbins) {
  __shared__ int cur[1024];
  int tid = threadIdx.x;
  int blk = blockIdx.x;
  for (int i = tid; i < nbins; i += 256) cur[i] = subPtr[i * nblk + blk];
  __syncthreads();
  int e0 = blk * EPB;
  int e1 = min(nE, e0 + EPB);
  if (e1 - e0 == EPB) {
#pragma unroll
    for (int it = 0; it < EPB / 1024; ++it) {
      int base = e0 + it * 1024 + tid * 4;
      int4 s = *(const int4*)(src + base);
      int4 d = *(const int4*)(dst + base);
      int p0 = atomicAdd(&cur[d.x >> 7], 1);
      int p1 = atomicAdd(&cur[d.y >> 7], 1);
      int p2 = atomicAdd(&cur[d.z >> 7], 1);
      int p3 = atomicAdd(&cur[d.w >> 7], 1);
      binned[p0] = s.x | ((d.x & 127) << 20);
      binned[p1] = s.y | ((d.y & 127) << 20);
      binned[p2] = s.z | ((d.z & 127) << 20);
      binned[p3] = s.w | ((d.w & 127) << 20);
    }
  } else {
    for (int i = e0 + tid; i < e1; i += 256) {
      int d = dst[i];
      int pos = atomicAdd(&cur[d >> 7], 1);
      binned[pos] = src[i] | ((d & 127) << 20);
    }
  }
}

__global__ __launch_bounds__(256) void k_bin_cnt(
    const int* __restrict__ binned, const int* __restrict__ subPtr,
    int* __restrict__ cnt, int nE, int nblk, int nbins, int n) {
  __shared__ int c128[128];
  int b = blockIdx.x;
  int tid = threadIdx.x;
  if (tid < 128) c128[tid] = 0;
  __syncthreads();
  int s0 = subPtr[b * nblk];
  int s1 = (b + 1 < nbins) ? subPtr[(b + 1) * nblk] : nE;
  for (int i = s0 + tid; i < s1; i += 256)
    atomicAdd(&c128[(binned[i] >> 20) & 127], 1);
  __syncthreads();
  if (tid < 128) {
    int idx = (b << 7) + tid;
    if (idx < n) cnt[idx] = c128[tid];
  }
}

__global__ __launch_bounds__(256) void k_bin_place(
    const int* __restrict__ binned, const int* __restrict__ subPtr,
    const int* __restrict__ rowptr, int* __restrict__ col, int nE, int nblk, int nbins, int n) {
  __shared__ int cur128[128];
  int b = blockIdx.x;
  int tid = threadIdx.x;
  if (tid < 128) {
    int idx = (b << 7) + tid;
    cur128[tid] = (idx < n) ? rowptr[idx] : 0;
  }
  __syncthreads();
  int s0 = subPtr[b * nblk];
  int s1 = (b + 1 < nbins) ? subPtr[(b + 1) * nblk] : nE;
  for (int i = s0 + tid; i < s1; i += 256) {
    int e = binned[i];
    int pos = atomicAdd(&cur128[(e >> 20) & 127], 1);
    col[pos] = e & 0xFFFFF;
  }
}

// ---- 3-phase exclusive scan ----

__global__ void k_blocksum(const int* __restrict__ cnt, int* __restrict__ bsum, int n) {
  __shared__ int red[256];
  int tid = threadIdx.x;
  int base = blockIdx.x * 1024 + tid * 4;
  int s = 0;
#pragma unroll
  for (int i = 0; i < 4; i++) { int idx = base + i; if (idx < n) s += cnt[idx]; }
  red[tid] = s;
  __syncthreads();
  for (int off = 128; off > 0; off >>= 1) {
    if (tid < off) red[tid] += red[tid + off];
    __syncthreads();
  }
  if (tid == 0) bsum[blockIdx.x] = red[0];
}

__global__ void k_scan_bsum(int* __restrict__ bsum, int nb) {
  __shared__ int s[128];
  int tid = threadIdx.x;
  int v = (tid < nb) ? bsum[tid] : 0;
  s[tid] = v;
  __syncthreads();
  for (int off = 1; off < 128; off <<= 1) {
    int t = (tid >= off) ? s[tid - off] : 0;
    __syncthreads();
    s[tid] += t;
    __syncthreads();
  }
  if (tid < nb) bsum[tid] = s[tid] - v;  // exclusive
}

__global__ void k_scan_final(const int* __restrict__ cnt, const int* __restrict__ bsum,
                             int* __restrict__ rowptr, float* __restrict__ dinv, int n) {
  __shared__ int tsum[256];
  int tid = threadIdx.x;
  int base = blockIdx.x * 1024 + tid * 4;
  int v[4]; int s = 0;
#pragma unroll
  for (int i = 0; i < 4; i++) { v[i] = (base + i < n) ? cnt[base + i] : 0; s += v[i]; }
  tsum[tid] = s;
  __syncthreads();
  for (int off = 1; off < 256; off <<= 1) {
    int t = (tid >= off) ? tsum[tid - off] : 0;
    __syncthreads();
    tsum[tid] += t;
    __syncthreads();
  }
  int run = bsum[blockIdx.x] + tsum[tid] - s;
#pragma unroll
  for (int i = 0; i < 4; i++) {
    int idx = base + i;
    if (idx < n) {
      rowptr[idx] = run;
      if (dinv) dinv[idx] = rsqrtf((float)(v[i] + 1));  // +1 self-loop
      run += v[i];
    }
  }
}

// ---- weight prep: fp16 + transpose; fuse Wmu|Wls, bmu|bls ----

__global__ void k_prep_w(const float* __restrict__ W1,
                         const float* __restrict__ Wmu, const float* __restrict__ Wls,
                         const float* __restrict__ bmu, const float* __restrict__ bls,
                         __half* __restrict__ W1T, __half* __restrict__ WcT,
                         float* __restrict__ bcat) {
  int i = blockIdx.x * blockDim.x + threadIdx.x;
  if (i < 128 * 256) {                     // W1T [n][k]
    int n = i >> 8, k = i & 255;
    W1T[i] = __float2half(W1[k * 128 + n]);
  } else if (i < 2 * 128 * 256) {          // WcT [n][k]
    int j = i - 128 * 256;
    int n = j >> 7, k = j & 127;
    float f = (n < 128) ? Wmu[k * 128 + n] : Wls[k * 128 + (n - 128)];
    WcT[j] = __float2half(f);
  } else if (i < 2 * 128 * 256 + 256) {    // bcat
    int n = i - 2 * 128 * 256;
    bcat[n] = (n < 128) ? bmu[n] : bls[n - 128];
  }
}

// ---------------- MFMA GEMM (round-10 structure, fp16 x fp16) — GEMM1 ----------------
// Measured 69us. BM=128, BN=128, BK=32, 4 waves 2x2. f32 A cvt in staging, fp16 out.

#define LP 40  // LDS row stride in halves

__global__ __launch_bounds__(256) void k_gemm_mfma(
    const float* __restrict__ Av, const __half* __restrict__ WT,
    __half* __restrict__ out0, int M, int K) {
  __shared__ _Float16 As[128 * LP];
  __shared__ _Float16 Bs[128 * LP];

  const int tid = threadIdx.x;
  const int lane = tid & 63;
  const int wv = tid >> 6;
  const int wr = wv >> 1, wc = wv & 1;
  const int rsel = lane >> 4;
  const int rrow = lane & 15;
  const int row0 = blockIdx.x * 128;
  const int col0 = 0;

  f32x4 acc[4][4];
#pragma unroll
  for (int m = 0; m < 4; m++)
#pragma unroll
    for (int n = 0; n < 4; n++) acc[m][n] = (f32x4){0.f, 0.f, 0.f, 0.f};

  const int srow = tid >> 1;
  const int skh = (tid & 1) * 16;

  for (int k0 = 0; k0 < K; k0 += 32) {
    if (row0 + srow < M) {
      const float* src = Av + (size_t)(row0 + srow) * K + k0 + skh;
      float4 f0 = *(const float4*)(src);
      float4 f1 = *(const float4*)(src + 4);
      float4 f2 = *(const float4*)(src + 8);
      float4 f3 = *(const float4*)(src + 12);
      f16x8 v0, v1;
      v0[0]=(_Float16)f0.x; v0[1]=(_Float16)f0.y; v0[2]=(_Float16)f0.z; v0[3]=(_Float16)f0.w;
      v0[4]=(_Float16)f1.x; v0[5]=(_Float16)f1.y; v0[6]=(_Float16)f1.z; v0[7]=(_Float16)f1.w;
      v1[0]=(_Float16)f2.x; v1[1]=(_Float16)f2.y; v1[2]=(_Float16)f2.z; v1[3]=(_Float16)f2.w;
      v1[4]=(_Float16)f3.x; v1[5]=(_Float16)f3.y; v1[6]=(_Float16)f3.z; v1[7]=(_Float16)f3.w;
      *(f16x8*)&As[srow * LP + skh]     = v0;
      *(f16x8*)&As[srow * LP + skh + 8] = v1;
    } else {
      f16x8 z = (f16x8){0,0,0,0,0,0,0,0};
      *(f16x8*)&As[srow * LP + skh] = z; *(f16x8*)&As[srow * LP + skh + 8] = z;
    }
    {
      const _Float16* s = (const _Float16*)WT + (size_t)(col0 + srow) * K + k0 + skh;
      *(f16x8*)&Bs[srow * LP + skh]     = *(const f16x8*)s;
      *(f16x8*)&Bs[srow * LP + skh + 8] = *(const f16x8*)(s + 8);
    }
    __syncthreads();

    f16x8 fa[4], fb[4];
#pragma unroll
    for (int m = 0; m < 4; m++)
      fa[m] = *(f16x8*)&As[(wr * 64 + m * 16 + rrow) * LP + rsel * 8];
#pragma unroll
    for (int n = 0; n < 4; n++)
      fb[n] = *(f16x8*)&Bs[(wc * 64 + n * 16 + rrow) * LP + rsel * 8];
#pragma unroll
    for (int m = 0; m < 4; m++)
#pragma unroll
      for (int n = 0; n < 4; n++)
        acc[m][n] = __builtin_amdgcn_mfma_f32_16x16x32_f16(fa[m], fb[n], acc[m][n], 0, 0, 0);
    __syncthreads();
  }

#pragma unroll
  for (int n = 0; n < 4; n++) {
    int c = col0 + wc * 64 + n * 16 + rrow;
#pragma unroll
    for (int m = 0; m < 4; m++) {
      f32x4 v = acc[m][n];
#pragma unroll
      for (int r = 0; r < 4; r++) {
        int row = row0 + wr * 64 + m * 16 + rsel * 4 + r;
        if (row < M) out0[(size_t)row * 128 + c] = __float2half(v[r]);
      }
    }
  }
}

// ---------------- pull-based SpMM (fp16 rows, on-the-fly norm) ----------------

__global__ __launch_bounds__(256) void k_spmm_h(
    const __half* __restrict__ in, const int* __restrict__ rowptr,
    const int* __restrict__ cnt, const int* __restrict__ col,
    const float* __restrict__ dinv,
    const float* __restrict__ bias, __half* __restrict__ out,
    int n, int use_bias, int relu_out) {
  int node = blockIdx.x * 4 + (threadIdx.x >> 6);
  if (node >= n) return;
  int lane = threadIdx.x & 63;

  const __half2* inp = (const __half2*)in;
  float di = dinv[node];
  float2 v = __half22float2(inp[(size_t)node * 64 + lane]);
  float accx = di * v.x;
  float accy = di * v.y;

  int beg = rowptr[node];
  int m = cnt[node];
  int i = 0;
  for (; i + 8 <= m; i += 8) {
    int c[8];
#pragma unroll
    for (int j = 0; j < 8; j++) c[j] = col[beg + i + j];
    float e[8];
#pragma unroll
    for (int j = 0; j < 8; j++) e[j] = dinv[c[j]];
    float2 u[8];
#pragma unroll
    for (int j = 0; j < 8; j++) u[j] = __half22float2(inp[(size_t)c[j] * 64 + lane]);
#pragma unroll
    for (int j = 0; j < 8; j++) { accx += e[j] * u[j].x; accy += e[j] * u[j].y; }
  }
  if (i < m) {
    int c[8];
#pragma unroll
    for (int j = 0; j < 8; j++) c[j] = col[(i + j < m) ? (beg + i + j) : beg];
    float e[8];
#pragma unroll
    for (int j = 0; j < 8; j++) e[j] = (i + j < m) ? dinv[c[j]] : 0.f;
    float2 u[8];
#pragma unroll
    for (int j = 0; j < 8; j++) u[j] = __half22float2(inp[(size_t)c[j] * 64 + lane]);
#pragma unroll
    for (int j = 0; j < 8; j++) { accx += e[j] * u[j].x; accy += e[j] * u[j].y; }
  }
  accx *= di;
  accy *= di;
  if (use_bias) {
    accx += bias[2 * lane];
    accy += bias[2 * lane + 1];
  }
  if (relu_out) {
    accx = fmaxf(accx, 0.f);
    accy = fmaxf(accy, 0.f);
  }
  ((__half2*)(out + (size_t)node * 128))[lane] = __floats2half2_rn(accx, accy);
}

// ---------------- fused SpMM2 + GEMM2: [mu|ls] = (A h) @ [Wmu|Wls] + b ----------------
// Block = 16 nodes, 512 thr = 8 waves x 2 nodes (unrolled -> 16 gathers in flight/wave).
// Phase 1: gather g-rows -> swizzled LDS (4KB). Phase 2: MFMA, 2 col-tiles/wave.

__global__ __launch_bounds__(512) void k_spmm_gemm(
    const __half* __restrict__ in, const int* __restrict__ rowptr,
    const int* __restrict__ cnt, const int* __restrict__ col,
    const float* __restrict__ dinv,
    const __half* __restrict__ WcT, const float* __restrict__ bcat,
    float* __restrict__ out0, float* __restrict__ out1, int n) {
  __shared__ _Float16 gt[16 * 128];   // 16 rows x 256B, 16B-chunk XOR-swizzled by row
  const int tid = threadIdx.x;
  const int lane = tid & 63;
  const int w = tid >> 6;             // 0..7
  const __half2* inp = (const __half2*)in;

  // ---- phase 1: 2 g-rows per wave, unrolled for cross-node MLP ----
#pragma unroll
  for (int q = 0; q < 2; q++) {
    int li = w * 2 + q;
    int node = blockIdx.x * 16 + li;
    float accx = 0.f, accy = 0.f;
    if (node < n) {
      float di = dinv[node];
      float2 v = __half22float2(inp[(size_t)node * 64 + lane]);
      accx = di * v.x;
      accy = di * v.y;
      int beg = rowptr[node];
      int m = cnt[node];
      int i = 0;
      for (; i + 8 <= m; i += 8) {
        int c[8];
#pragma unroll
        for (int j = 0; j < 8; j++) c[j] = col[beg + i + j];
        float e[8];
#pragma unroll
        for (int j = 0; j < 8; j++) e[j] = dinv[c[j]];
        float2 u[8];
#pragma unroll
        for (int j = 0; j < 8; j++) u[j] = __half22float2(inp[(size_t)c[j] * 64 + lane]);
#pragma unroll
        for (int j = 0; j < 8; j++) { accx += e[j] * u[j].x; accy += e[j] * u[j].y; }
      }
      if (i < m) {
        int c[8];
#pragma unroll
        for (int j = 0; j < 8; j++) c[j] = col[(i + j < m) ? (beg + i + j) : beg];
        float e[8];
#pragma unroll
        for (int j = 0; j < 8; j++) e[j] = (i + j < m) ? dinv[c[j]] : 0.f;
        float2 u[8];
#pragma unroll
        for (int j = 0; j < 8; j++) u[j] = __half22float2(inp[(size_t)c[j] * 64 + lane]);
#pragma unroll
        for (int j = 0; j < 8; j++) { accx += e[j] * u[j].x; accy += e[j] * u[j].y; }
      }
      accx *= di;
      accy *= di;
    }
    int slot = (lane >> 2) ^ (li & 7);
    *(__half2*)((char*)gt + li * 256 + slot * 16 + (lane & 3) * 4) =
        __floats2half2_rn(accx, accy);
  }
  __syncthreads();

  // ---- phase 2: MFMA 16 rows x 256 cols, wave w owns col-tiles w*2, w*2+1 ----
  const int lr = lane & 15;
  const int lk = lane >> 4;
  f16x8 a[4];
#pragma unroll
  for (int ks = 0; ks < 4; ks++) {
    int slot = (ks * 4 + lk) ^ (lr & 7);
    a[ks] = *(const f16x8*)((const char*)gt + lr * 256 + slot * 16);
  }
#pragma unroll
  for (int ct = 0; ct < 2; ct++) {
    int colg = (w * 2 + ct) * 16 + lr;    // 0..255
    f32x4 acc = (f32x4){0.f, 0.f, 0.f, 0.f};
#pragma unroll
    for (int ks = 0; ks < 4; ks++) {
      f16x8 b = *(const f16x8*)((const _Float16*)WcT + (size_t)colg * 128 + ks * 32 + lk * 8);
      acc = __builtin_amdgcn_mfma_f32_16x16x32_f16(a[ks], b, acc, 0, 0, 0);
    }
    float badd = bcat[colg];
    float* dst = out0;
    int c = colg;
    if (c >= 128) { dst = out1; c -= 128; }
#pragma unroll
    for (int r = 0; r < 4; r++) {
      int node = blockIdx.x * 16 + lk * 4 + r;
      if (node < n) dst[(size_t)node * 128 + c] = acc[r] + badd;
    }
  }
}

// ---------------- launch ----------------

extern "C" void kernel_launch(void* const* d_in, const int* in_sizes, int n_in,
                              void* d_out, int out_size, void* d_ws, size_t ws_size,
                              hipStream_t stream) {
  const float* x   = (const float*)d_in[0];
  const int*   ei  = (const int*)d_in[1];
  const float* W1  = (const float*)d_in[2];
  const float* b1  = (const float*)d_in[3];
  const float* Wmu = (const float*)d_in[4];
  const float* bmu = (const float*)d_in[5];
  const float* Wls = (const float*)d_in[6];
  const float* bls = (const float*)d_in[7];

  int N = in_sizes[0] / 256;
  int E = in_sizes[1] / 2;
  const int* src = ei;
  const int* dst = ei + E;

  int NBINS = (N + 127) >> 7;
  int NBLK  = (E + EPB - 1) / EPB;
  int NS    = NBINS * NBLK;

  char* ws = (char*)d_ws;
  size_t o = 0;
  auto alloc = [&](size_t b) { size_t c = o; o = (o + b + 511) & ~(size_t)511; return c; };
  int*   cnt     = (int*)(ws + alloc((size_t)N * 4));
  int*   rowptr  = (int*)(ws + alloc((size_t)N * 4));
  float* dinv    = (float*)(ws + alloc((size_t)N * 4));
  int*   bsum    = (int*)(ws + alloc(512));
  int*   histT   = (int*)(ws + alloc((size_t)NS * 4));
  int*   subPtr  = (int*)(ws + alloc((size_t)NS * 4));
  int*   col     = (int*)(ws + alloc((size_t)E * 4));
  int*   binned  = (int*)(ws + alloc((size_t)E * 4));
  __half* W1T  = (__half*)(ws + alloc(128 * 256 * 2));
  __half* WcT  = (__half*)(ws + alloc(256 * 128 * 2));
  float*  bcat = (float*)(ws + alloc(256 * 4));
  __half* h0   = (__half*)(ws + alloc((size_t)N * 128 * 2));  // GEMM1 out
  __half* hBuf = (__half*)(ws + alloc((size_t)N * 128 * 2));  // h (relu'd)

  float* outMu = (float*)d_out;
  float* outLs = outMu + (size_t)N * 128;

  int nbScanN = (N + 1023) / 1024;
  int nbScanS = (NS + 1023) / 1024;

  // ---- CSR build (counting sort by bin, block-private windows) ----
  k_lhist<<<NBLK, 256, 0, stream>>>(dst, histT, E, NBLK, NBINS);
  k_blocksum<<<nbScanS, 256, 0, stream>>>(histT, bsum, NS);
  k_scan_bsum<<<1, 128, 0, stream>>>(bsum, nbScanS);
  k_scan_final<<<nbScanS, 256, 0, stream>>>(histT, bsum, subPtr, nullptr, NS);
  k_lscatter<<<NBLK, 256, 0, stream>>>(src, dst, subPtr, binned, E, NBLK, NBINS);
  k_bin_cnt<<<NBINS, 256, 0, stream>>>(binned, subPtr, cnt, E, NBLK, NBINS, N);
  k_blocksum<<<nbScanN, 256, 0, stream>>>(cnt, bsum, N);
  k_scan_bsum<<<1, 128, 0, stream>>>(bsum, nbScanN);
  k_scan_final<<<nbScanN, 256, 0, stream>>>(cnt, bsum, rowptr, dinv, N);
  k_bin_place<<<NBINS, 256, 0, stream>>>(binned, subPtr, rowptr, col, E, NBLK, NBINS, N);

  // ---- weights ----
  k_prep_w<<<(2 * 128 * 256 + 256 + 255) / 256, 256, 0, stream>>>(
      W1, Wmu, Wls, bmu, bls, W1T, WcT, bcat);

  // h0 = x @ W1                 [N,128] fp16 (round-10 structure, 69us measured)
  k_gemm_mfma<<<(N + 127) / 128, 256, 0, stream>>>(x, W1T, h0, N, 256);
  // h = relu(A h0 + b1)         [N,128] fp16
  k_spmm_h<<<(N + 3) / 4, 256, 0, stream>>>(h0, rowptr, cnt, col, dinv, b1, hBuf, N, 1, 1);
  // [mu|ls] = (A h) @ [Wmu|Wls] + [bmu|bls]   fused: g stays in LDS
  k_spmm_gemm<<<(N + 15) / 16, 512, 0, stream>>>(
      hBuf, rowptr, cnt, col, dinv, WcT, bcat, outMu, outLs, N);
}

// Round 17
// 289.914 us; speedup vs baseline: 1.1128x; 1.0369x over previous
//
#include <hip/hip_runtime.h>
#include <hip/hip_bf16.h>
#include <hip/hip_fp16.h>

typedef __attribute__((ext_vector_type(8))) short short8;
typedef __attribute__((ext_vector_type(8))) _Float16 f16x8;
typedef __attribute__((ext_vector_type(4))) float f32x4;

// ================= CSR build: two-pass counting sort by dst-bin =================
#define EPB 16384

__global__ __launch_bounds__(256) void k_lhist(const int* __restrict__ dst, int* __restrict__ histT,
                                               int nE, int nblk, int nbins) {
  __shared__ int c[1024];
  int tid = threadIdx.x;
  for (int i = tid; i < nbins; i += 256) c[i] = 0;
  __syncthreads();
  int blk = blockIdx.x;
  int e0 = blk * EPB;
  int e1 = min(nE, e0 + EPB);
  if (e1 - e0 == EPB) {
#pragma unroll
    for (int it = 0; it < EPB / 1024; ++it) {
      int4 d = *(const int4*)(dst + e0 + it * 1024 + tid * 4);
      atomicAdd(&c[d.x >> 7], 1);
      atomicAdd(&c[d.y >> 7], 1);
      atomicAdd(&c[d.z >> 7], 1);
      atomicAdd(&c[d.w >> 7], 1);
    }
  } else {
    for (int i = e0 + tid; i < e1; i += 256) atomicAdd(&c[dst[i] >> 7], 1);
  }
  __syncthreads();
  for (int i = tid; i < nbins; i += 256) histT[i * nblk + blk] = c[i];
}

__global__ __launch_bounds__(256) void k_lscatter(
    const int* __restrict__ src, const int* __restrict__ dst, const int* __restrict__ subPtr,
    int* __restrict__ binned, int nE, int nblk, int nbins) {
  __shared__ int cur[1024];
  int tid = threadIdx.x;
  int blk = blockIdx.x;
  for (int i = tid; i < nbins; i += 256) cur[i] = subPtr[i * nblk + blk];
  __syncthreads();
  int e0 = blk * EPB;
  int e1 = min(nE, e0 + EPB);
  if (e1 - e0 == EPB) {
#pragma unroll
    for (int it = 0; it < EPB / 1024; ++it) {
      int base = e0 + it * 1024 + tid * 4;
      int4 s = *(const int4*)(src + base);
      int4 d = *(const int4*)(dst + base);
      int p0 = atomicAdd(&cur[d.x >> 7], 1);
      int p1 = atomicAdd(&cur[d.y >> 7], 1);
      int p2 = atomicAdd(&cur[d.z >> 7], 1);
      int p3 = atomicAdd(&cur[d.w >> 7], 1);
      binned[p0] = s.x | ((d.x & 127) << 20);
      binned[p1] = s.y | ((d.y & 127) << 20);
      binned[p2] = s.z | ((d.z & 127) << 20);
      binned[p3] = s.w | ((d.w & 127) << 20);
    }
  } else {
    for (int i = e0 + tid; i < e1; i += 256) {
      int d = dst[i];
      int pos = atomicAdd(&cur[d >> 7], 1);
      binned[pos] = src[i] | ((d & 127) << 20);
    }
  }
}

// ---- fused bin finish: count -> LDS scan -> cnt/rowptr/dinv -> place ----
// One block per bin. rowptr[node] = binStart + exclusive-prefix(local degree).
// Eliminates the N-scan chain and one full re-read pass of `binned`.

__global__ __launch_bounds__(256) void k_bin_finish(
    const int* __restrict__ binned, const int* __restrict__ subPtr,
    int* __restrict__ cnt, int* __restrict__ rowptr, float* __restrict__ dinv,
    int* __restrict__ col, int nE, int nblk, int nbins, int n) {
  __shared__ int c128[128];
  __shared__ int scan128[128];
  __shared__ int cur128[128];
  int b = blockIdx.x;
  int tid = threadIdx.x;
  if (tid < 128) c128[tid] = 0;
  __syncthreads();
  int s0 = subPtr[b * nblk];
  int s1 = (b + 1 < nbins) ? subPtr[(b + 1) * nblk] : nE;
  for (int i = s0 + tid; i < s1; i += 256)
    atomicAdd(&c128[(binned[i] >> 20) & 127], 1);
  __syncthreads();
  // exclusive scan over 128 local degrees (Hillis-Steele, 7 steps)
  if (tid < 128) scan128[tid] = c128[tid];
  __syncthreads();
  for (int off = 1; off < 128; off <<= 1) {
    int t = 0;
    if (tid < 128 && tid >= off) t = scan128[tid - off];
    __syncthreads();
    if (tid < 128) scan128[tid] += t;
    __syncthreads();
  }
  if (tid < 128) {
    int v = c128[tid];
    int excl = scan128[tid] - v;
    int rp = s0 + excl;
    int idx = (b << 7) + tid;
    if (idx < n) {
      cnt[idx] = v;
      rowptr[idx] = rp;
      dinv[idx] = rsqrtf((float)(v + 1));  // +1 self-loop
    }
    cur128[tid] = rp;
  }
  __syncthreads();
  for (int i = s0 + tid; i < s1; i += 256) {
    int e = binned[i];
    int pos = atomicAdd(&cur128[(e >> 20) & 127], 1);
    col[pos] = e & 0xFFFFF;
  }
}

// ---- 3-phase exclusive scan (used for the NS hist matrix only) ----

__global__ void k_blocksum(const int* __restrict__ cnt, int* __restrict__ bsum, int n) {
  __shared__ int red[256];
  int tid = threadIdx.x;
  int base = blockIdx.x * 1024 + tid * 4;
  int s = 0;
#pragma unroll
  for (int i = 0; i < 4; i++) { int idx = base + i; if (idx < n) s += cnt[idx]; }
  red[tid] = s;
  __syncthreads();
  for (int off = 128; off > 0; off >>= 1) {
    if (tid < off) red[tid] += red[tid + off];
    __syncthreads();
  }
  if (tid == 0) bsum[blockIdx.x] = red[0];
}

__global__ void k_scan_bsum(int* __restrict__ bsum, int nb) {
  __shared__ int s[128];
  int tid = threadIdx.x;
  int v = (tid < nb) ? bsum[tid] : 0;
  s[tid] = v;
  __syncthreads();
  for (int off = 1; off < 128; off <<= 1) {
    int t = (tid >= off) ? s[tid - off] : 0;
    __syncthreads();
    s[tid] += t;
    __syncthreads();
  }
  if (tid < nb) bsum[tid] = s[tid] - v;  // exclusive
}

__global__ void k_scan_final(const int* __restrict__ cnt, const int* __restrict__ bsum,
                             int* __restrict__ rowptr, int n) {
  __shared__ int tsum[256];
  int tid = threadIdx.x;
  int base = blockIdx.x * 1024 + tid * 4;
  int v[4]; int s = 0;
#pragma unroll
  for (int i = 0; i < 4; i++) { v[i] = (base + i < n) ? cnt[base + i] : 0; s += v[i]; }
  tsum[tid] = s;
  __syncthreads();
  for (int off = 1; off < 256; off <<= 1) {
    int t = (tid >= off) ? tsum[tid - off] : 0;
    __syncthreads();
    tsum[tid] += t;
    __syncthreads();
  }
  int run = bsum[blockIdx.x] + tsum[tid] - s;
#pragma unroll
  for (int i = 0; i < 4; i++) {
    int idx = base + i;
    if (idx < n) { rowptr[idx] = run; run += v[i]; }
  }
}

// ---- weight prep: fp16 + transpose; fuse Wmu|Wls, bmu|bls ----

__global__ void k_prep_w(const float* __restrict__ W1,
                         const float* __restrict__ Wmu, const float* __restrict__ Wls,
                         const float* __restrict__ bmu, const float* __restrict__ bls,
                         __half* __restrict__ W1T, __half* __restrict__ WcT,
                         float* __restrict__ bcat) {
  int i = blockIdx.x * blockDim.x + threadIdx.x;
  if (i < 128 * 256) {                     // W1T [n][k]
    int n = i >> 8, k = i & 255;
    W1T[i] = __float2half(W1[k * 128 + n]);
  } else if (i < 2 * 128 * 256) {          // WcT [n][k]
    int j = i - 128 * 256;
    int n = j >> 7, k = j & 127;
    float f = (n < 128) ? Wmu[k * 128 + n] : Wls[k * 128 + (n - 128)];
    WcT[j] = __float2half(f);
  } else if (i < 2 * 128 * 256 + 256) {    // bcat
    int n = i - 2 * 128 * 256;
    bcat[n] = (n < 128) ? bmu[n] : bls[n - 128];
  }
}

// ---------------- MFMA GEMM (round-10 structure) — GEMM1 ----------------

#define LP 40  // LDS row stride in halves

__global__ __launch_bounds__(256) void k_gemm_mfma(
    const float* __restrict__ Av, const __half* __restrict__ WT,
    __half* __restrict__ out0, int M, int K) {
  __shared__ _Float16 As[128 * LP];
  __shared__ _Float16 Bs[128 * LP];

  const int tid = threadIdx.x;
  const int lane = tid & 63;
  const int wv = tid >> 6;
  const int wr = wv >> 1, wc = wv & 1;
  const int rsel = lane >> 4;
  const int rrow = lane & 15;
  const int row0 = blockIdx.x * 128;

  f32x4 acc[4][4];
#pragma unroll
  for (int m = 0; m < 4; m++)
#pragma unroll
    for (int n = 0; n < 4; n++) acc[m][n] = (f32x4){0.f, 0.f, 0.f, 0.f};

  const int srow = tid >> 1;
  const int skh = (tid & 1) * 16;

  for (int k0 = 0; k0 < K; k0 += 32) {
    if (row0 + srow < M) {
      const float* src = Av + (size_t)(row0 + srow) * K + k0 + skh;
      float4 f0 = *(const float4*)(src);
      float4 f1 = *(const float4*)(src + 4);
      float4 f2 = *(const float4*)(src + 8);
      float4 f3 = *(const float4*)(src + 12);
      f16x8 v0, v1;
      v0[0]=(_Float16)f0.x; v0[1]=(_Float16)f0.y; v0[2]=(_Float16)f0.z; v0[3]=(_Float16)f0.w;
      v0[4]=(_Float16)f1.x; v0[5]=(_Float16)f1.y; v0[6]=(_Float16)f1.z; v0[7]=(_Float16)f1.w;
      v1[0]=(_Float16)f2.x; v1[1]=(_Float16)f2.y; v1[2]=(_Float16)f2.z; v1[3]=(_Float16)f2.w;
      v1[4]=(_Float16)f3.x; v1[5]=(_Float16)f3.y; v1[6]=(_Float16)f3.z; v1[7]=(_Float16)f3.w;
      *(f16x8*)&As[srow * LP + skh]     = v0;
      *(f16x8*)&As[srow * LP + skh + 8] = v1;
    } else {
      f16x8 z = (f16x8){0,0,0,0,0,0,0,0};
      *(f16x8*)&As[srow * LP + skh] = z; *(f16x8*)&As[srow * LP + skh + 8] = z;
    }
    {
      const _Float16* s = (const _Float16*)WT + (size_t)srow * K + k0 + skh;
      *(f16x8*)&Bs[srow * LP + skh]     = *(const f16x8*)s;
      *(f16x8*)&Bs[srow * LP + skh + 8] = *(const f16x8*)(s + 8);
    }
    __syncthreads();

    f16x8 fa[4], fb[4];
#pragma unroll
    for (int m = 0; m < 4; m++)
      fa[m] = *(f16x8*)&As[(wr * 64 + m * 16 + rrow) * LP + rsel * 8];
#pragma unroll
    for (int n = 0; n < 4; n++)
      fb[n] = *(f16x8*)&Bs[(wc * 64 + n * 16 + rrow) * LP + rsel * 8];
#pragma unroll
    for (int m = 0; m < 4; m++)
#pragma unroll
      for (int n = 0; n < 4; n++)
        acc[m][n] = __builtin_amdgcn_mfma_f32_16x16x32_f16(fa[m], fb[n], acc[m][n], 0, 0, 0);
    __syncthreads();
  }

#pragma unroll
  for (int n = 0; n < 4; n++) {
    int c = wc * 64 + n * 16 + rrow;
#pragma unroll
    for (int m = 0; m < 4; m++) {
      f32x4 v = acc[m][n];
#pragma unroll
      for (int r = 0; r < 4; r++) {
        int row = row0 + wr * 64 + m * 16 + rsel * 4 + r;
        if (row < M) out0[(size_t)row * 128 + c] = __float2half(v[r]);
      }
    }
  }
}

// ---------------- pull-based SpMM (fp16 rows, on-the-fly norm) ----------------

__global__ __launch_bounds__(256) void k_spmm_h(
    const __half* __restrict__ in, const int* __restrict__ rowptr,
    const int* __restrict__ cnt, const int* __restrict__ col,
    const float* __restrict__ dinv,
    const float* __restrict__ bias, __half* __restrict__ out,
    int n, int use_bias, int relu_out) {
  int node = blockIdx.x * 4 + (threadIdx.x >> 6);
  if (node >= n) return;
  int lane = threadIdx.x & 63;

  const __half2* inp = (const __half2*)in;
  float di = dinv[node];
  float2 v = __half22float2(inp[(size_t)node * 64 + lane]);
  float accx = di * v.x;
  float accy = di * v.y;

  int beg = rowptr[node];
  int m = cnt[node];
  int i = 0;
  for (; i + 8 <= m; i += 8) {
    int c[8];
#pragma unroll
    for (int j = 0; j < 8; j++) c[j] = col[beg + i + j];
    float e[8];
#pragma unroll
    for (int j = 0; j < 8; j++) e[j] = dinv[c[j]];
    float2 u[8];
#pragma unroll
    for (int j = 0; j < 8; j++) u[j] = __half22float2(inp[(size_t)c[j] * 64 + lane]);
#pragma unroll
    for (int j = 0; j < 8; j++) { accx += e[j] * u[j].x; accy += e[j] * u[j].y; }
  }
  if (i < m) {
    int c[8];
#pragma unroll
    for (int j = 0; j < 8; j++) c[j] = col[(i + j < m) ? (beg + i + j) : beg];
    float e[8];
#pragma unroll
    for (int j = 0; j < 8; j++) e[j] = (i + j < m) ? dinv[c[j]] : 0.f;
    float2 u[8];
#pragma unroll
    for (int j = 0; j < 8; j++) u[j] = __half22float2(inp[(size_t)c[j] * 64 + lane]);
#pragma unroll
    for (int j = 0; j < 8; j++) { accx += e[j] * u[j].x; accy += e[j] * u[j].y; }
  }
  accx *= di;
  accy *= di;
  if (use_bias) {
    accx += bias[2 * lane];
    accy += bias[2 * lane + 1];
  }
  if (relu_out) {
    accx = fmaxf(accx, 0.f);
    accy = fmaxf(accy, 0.f);
  }
  ((__half2*)(out + (size_t)node * 128))[lane] = __floats2half2_rn(accx, accy);
}

// ---------------- fused SpMM2 + GEMM2 (round-14 structure, measured 113.8us) ----------------
// Block = 16 nodes, 4 waves x 4 nodes. Phase 1: gather g-rows -> swizzled LDS (4KB).
// Phase 2: 16x256 MFMA. g never touches global memory.

__global__ __launch_bounds__(256) void k_spmm_gemm(
    const __half* __restrict__ in, const int* __restrict__ rowptr,
    const int* __restrict__ cnt, const int* __restrict__ col,
    const float* __restrict__ dinv,
    const __half* __restrict__ WcT, const float* __restrict__ bcat,
    float* __restrict__ out0, float* __restrict__ out1, int n) {
  __shared__ _Float16 gt[16 * 128];   // 16 rows x 256B, 16B-chunk XOR-swizzled by row
  const int tid = threadIdx.x;
  const int lane = tid & 63;
  const int w = tid >> 6;
  const __half2* inp = (const __half2*)in;

  // ---- phase 1: 4 g-rows per wave ----
  for (int q = 0; q < 4; q++) {
    int li = w * 4 + q;
    int node = blockIdx.x * 16 + li;
    float accx = 0.f, accy = 0.f;
    if (node < n) {
      float di = dinv[node];
      float2 v = __half22float2(inp[(size_t)node * 64 + lane]);
      accx = di * v.x;
      accy = di * v.y;
      int beg = rowptr[node];
      int m = cnt[node];
      int i = 0;
      for (; i + 8 <= m; i += 8) {
        int c[8];
#pragma unroll
        for (int j = 0; j < 8; j++) c[j] = col[beg + i + j];
        float e[8];
#pragma unroll
        for (int j = 0; j < 8; j++) e[j] = dinv[c[j]];
        float2 u[8];
#pragma unroll
        for (int j = 0; j < 8; j++) u[j] = __half22float2(inp[(size_t)c[j] * 64 + lane]);
#pragma unroll
        for (int j = 0; j < 8; j++) { accx += e[j] * u[j].x; accy += e[j] * u[j].y; }
      }
      if (i < m) {
        int c[8];
#pragma unroll
        for (int j = 0; j < 8; j++) c[j] = col[(i + j < m) ? (beg + i + j) : beg];
        float e[8];
#pragma unroll
        for (int j = 0; j < 8; j++) e[j] = (i + j < m) ? dinv[c[j]] : 0.f;
        float2 u[8];
#pragma unroll
        for (int j = 0; j < 8; j++) u[j] = __half22float2(inp[(size_t)c[j] * 64 + lane]);
#pragma unroll
        for (int j = 0; j < 8; j++) { accx += e[j] * u[j].x; accy += e[j] * u[j].y; }
      }
      accx *= di;
      accy *= di;
    }
    int slot = (lane >> 2) ^ (li & 7);
    *(__half2*)((char*)gt + li * 256 + slot * 16 + (lane & 3) * 4) =
        __floats2half2_rn(accx, accy);
  }
  __syncthreads();

  // ---- phase 2: MFMA 16 rows x 256 cols ----
  const int lr = lane & 15;
  const int lk = lane >> 4;
  f16x8 a[4];
#pragma unroll
  for (int ks = 0; ks < 4; ks++) {
    int slot = (ks * 4 + lk) ^ (lr & 7);
    a[ks] = *(const f16x8*)((const char*)gt + lr * 256 + slot * 16);
  }
#pragma unroll
  for (int ct = 0; ct < 4; ct++) {
    int colg = (w * 4 + ct) * 16 + lr;    // 0..255
    f32x4 acc = (f32x4){0.f, 0.f, 0.f, 0.f};
#pragma unroll
    for (int ks = 0; ks < 4; ks++) {
      f16x8 b = *(const f16x8*)((const _Float16*)WcT + (size_t)colg * 128 + ks * 32 + lk * 8);
      acc = __builtin_amdgcn_mfma_f32_16x16x32_f16(a[ks], b, acc, 0, 0, 0);
    }
    float badd = bcat[colg];
    float* dst = out0;
    int c = colg;
    if (c >= 128) { dst = out1; c -= 128; }
#pragma unroll
    for (int r = 0; r < 4; r++) {
      int node = blockIdx.x * 16 + lk * 4 + r;
      if (node < n) dst[(size_t)node * 128 + c] = acc[r] + badd;
    }
  }
}

// ---------------- launch ----------------

extern "C" void kernel_launch(void* const* d_in, const int* in_sizes, int n_in,
                              void* d_out, int out_size, void* d_ws, size_t ws_size,
                              hipStream_t stream) {
  const float* x   = (const float*)d_in[0];
  const int*   ei  = (const int*)d_in[1];
  const float* W1  = (const float*)d_in[2];
  const float* b1  = (const float*)d_in[3];
  const float* Wmu = (const float*)d_in[4];
  const float* bmu = (const float*)d_in[5];
  const float* Wls = (const float*)d_in[6];
  const float* bls = (const float*)d_in[7];

  int N = in_sizes[0] / 256;
  int E = in_sizes[1] / 2;
  const int* src = ei;
  const int* dst = ei + E;

  int NBINS = (N + 127) >> 7;
  int NBLK  = (E + EPB - 1) / EPB;
  int NS    = NBINS * NBLK;

  char* ws = (char*)d_ws;
  size_t o = 0;
  auto alloc = [&](size_t b) { size_t c = o; o = (o + b + 511) & ~(size_t)511; return c; };
  int*   cnt     = (int*)(ws + alloc((size_t)N * 4));
  int*   rowptr  = (int*)(ws + alloc((size_t)N * 4));
  float* dinv    = (float*)(ws + alloc((size_t)N * 4));
  int*   bsum    = (int*)(ws + alloc(512));
  int*   histT   = (int*)(ws + alloc((size_t)NS * 4));
  int*   subPtr  = (int*)(ws + alloc((size_t)NS * 4));
  int*   col     = (int*)(ws + alloc((size_t)E * 4));
  int*   binned  = (int*)(ws + alloc((size_t)E * 4));
  __half* W1T  = (__half*)(ws + alloc(128 * 256 * 2));
  __half* WcT  = (__half*)(ws + alloc(256 * 128 * 2));
  float*  bcat = (float*)(ws + alloc(256 * 4));
  __half* h0   = (__half*)(ws + alloc((size_t)N * 128 * 2));  // GEMM1 out
  __half* hBuf = (__half*)(ws + alloc((size_t)N * 128 * 2));  // h (relu'd)

  float* outMu = (float*)d_out;
  float* outLs = outMu + (size_t)N * 128;

  int nbScanS = (NS + 1023) / 1024;

  // ---- CSR build: hist -> scan(NS) -> scatter -> fused bin-finish ----
  k_lhist<<<NBLK, 256, 0, stream>>>(dst, histT, E, NBLK, NBINS);
  k_blocksum<<<nbScanS, 256, 0, stream>>>(histT, bsum, NS);
  k_scan_bsum<<<1, 128, 0, stream>>>(bsum, nbScanS);
  k_scan_final<<<nbScanS, 256, 0, stream>>>(histT, bsum, subPtr, NS);
  k_lscatter<<<NBLK, 256, 0, stream>>>(src, dst, subPtr, binned, E, NBLK, NBINS);
  k_bin_finish<<<NBINS, 256, 0, stream>>>(binned, subPtr, cnt, rowptr, dinv, col,
                                          E, NBLK, NBINS, N);

  // ---- weights ----
  k_prep_w<<<(2 * 128 * 256 + 256 + 255) / 256, 256, 0, stream>>>(
      W1, Wmu, Wls, bmu, bls, W1T, WcT, bcat);

  // h0 = x @ W1                 [N,128] fp16 (round-10 structure)
  k_gemm_mfma<<<(N + 127) / 128, 256, 0, stream>>>(x, W1T, h0, N, 256);
  // h = relu(A h0 + b1)         [N,128] fp16
  k_spmm_h<<<(N + 3) / 4, 256, 0, stream>>>(h0, rowptr, cnt, col, dinv, b1, hBuf, N, 1, 1);
  // [mu|ls] = (A h) @ [Wmu|Wls] + [bmu|bls]   fused: g stays in LDS
  k_spmm_gemm<<<(N + 15) / 16, 256, 0, stream>>>(
      hBuf, rowptr, cnt, col, dinv, WcT, bcat, outMu, outLs, N);
}

// Round 18
// 270.874 us; speedup vs baseline: 1.1910x; 1.0703x over previous
//
#include <hip/hip_runtime.h>
#include <hip/hip_bf16.h>
#include <hip/hip_fp16.h>

typedef __attribute__((ext_vector_type(8))) short short8;
typedef __attribute__((ext_vector_type(8))) _Float16 f16x8;
typedef __attribute__((ext_vector_type(4))) float f32x4;

// ================= CSR build: fixed-capacity bins + per-block reservation =================
// bin = dst >> 7 (128 nodes/bin). Bin b owns binned[b*CAP .. b*CAP+count). Blocks reserve
// c[bin] slots via one global atomicAdd per (block,bin) -> block-private write runs.
// CAP=8192 vs mean load 2048 (uniform edges): overflow probability ~0.
#define EPB 16384
#define CAP_SHIFT 13
#define CAP (1 << CAP_SHIFT)

__global__ __launch_bounds__(256) void k_fused_scatter(
    const int* __restrict__ src, const int* __restrict__ dst,
    int* __restrict__ binCursor, int* __restrict__ binned, int nE, int nbins) {
  __shared__ int c[1024];
  int tid = threadIdx.x;
  for (int i = tid; i < nbins; i += 256) c[i] = 0;
  __syncthreads();
  int e0 = blockIdx.x * EPB;
  int e1 = min(nE, e0 + EPB);
  // phase A: LDS histogram of this chunk
  if (e1 - e0 == EPB) {
#pragma unroll
    for (int it = 0; it < EPB / 1024; ++it) {
      int4 d = *(const int4*)(dst + e0 + it * 1024 + tid * 4);
      atomicAdd(&c[d.x >> 7], 1);
      atomicAdd(&c[d.y >> 7], 1);
      atomicAdd(&c[d.z >> 7], 1);
      atomicAdd(&c[d.w >> 7], 1);
    }
  } else {
    for (int i = e0 + tid; i < e1; i += 256) atomicAdd(&c[dst[i] >> 7], 1);
  }
  __syncthreads();
  // phase B: reserve block-private windows inside each bin's region
  for (int i = tid; i < nbins; i += 256) {
    int v = c[i];
    int base = v ? atomicAdd(&binCursor[i], v) : 0;
    c[i] = (i << CAP_SHIFT) + base;
  }
  __syncthreads();
  // phase C: scatter (packed: src | (dst&127)<<20)
  if (e1 - e0 == EPB) {
#pragma unroll
    for (int it = 0; it < EPB / 1024; ++it) {
      int base = e0 + it * 1024 + tid * 4;
      int4 s = *(const int4*)(src + base);
      int4 d = *(const int4*)(dst + base);
      int p0 = atomicAdd(&c[d.x >> 7], 1);
      int p1 = atomicAdd(&c[d.y >> 7], 1);
      int p2 = atomicAdd(&c[d.z >> 7], 1);
      int p3 = atomicAdd(&c[d.w >> 7], 1);
      binned[p0] = s.x | ((d.x & 127) << 20);
      binned[p1] = s.y | ((d.y & 127) << 20);
      binned[p2] = s.z | ((d.z & 127) << 20);
      binned[p3] = s.w | ((d.w & 127) << 20);
    }
  } else {
    for (int i = e0 + tid; i < e1; i += 256) {
      int d = dst[i];
      int pos = atomicAdd(&c[d >> 7], 1);
      binned[pos] = src[i] | ((d & 127) << 20);
    }
  }
}

// ---- fused bin finish: count -> LDS scan -> cnt/rowptr/dinv -> place ----
// One block per bin. rowptr[node] = b*CAP + exclusive-prefix(local degree).
// col is gapped (CAP per bin) — SpMMs only use rowptr/cnt, so gaps are invisible.

__global__ __launch_bounds__(256) void k_bin_finish(
    const int* __restrict__ binned, const int* __restrict__ binCnt,
    int* __restrict__ cnt, int* __restrict__ rowptr, float* __restrict__ dinv,
    int* __restrict__ col, int nbins, int n) {
  __shared__ int c128[128];
  __shared__ int scan128[128];
  __shared__ int cur128[128];
  int b = blockIdx.x;
  int tid = threadIdx.x;
  if (tid < 128) c128[tid] = 0;
  __syncthreads();
  int s0 = b << CAP_SHIFT;
  int s1 = s0 + binCnt[b];
  for (int i = s0 + tid; i < s1; i += 256)
    atomicAdd(&c128[(binned[i] >> 20) & 127], 1);
  __syncthreads();
  if (tid < 128) scan128[tid] = c128[tid];
  __syncthreads();
  for (int off = 1; off < 128; off <<= 1) {
    int t = 0;
    if (tid < 128 && tid >= off) t = scan128[tid - off];
    __syncthreads();
    if (tid < 128) scan128[tid] += t;
    __syncthreads();
  }
  if (tid < 128) {
    int v = c128[tid];
    int rp = s0 + scan128[tid] - v;
    int idx = (b << 7) + tid;
    if (idx < n) {
      cnt[idx] = v;
      rowptr[idx] = rp;
      dinv[idx] = rsqrtf((float)(v + 1));  // +1 self-loop
    }
    cur128[tid] = rp;
  }
  __syncthreads();
  for (int i = s0 + tid; i < s1; i += 256) {
    int e = binned[i];
    int pos = atomicAdd(&cur128[(e >> 20) & 127], 1);
    col[pos] = e & 0xFFFFF;
  }
}

// ---- weight prep: fp16 + transpose; fuse Wmu|Wls, bmu|bls ----

__global__ void k_prep_w(const float* __restrict__ W1,
                         const float* __restrict__ Wmu, const float* __restrict__ Wls,
                         const float* __restrict__ bmu, const float* __restrict__ bls,
                         __half* __restrict__ W1T, __half* __restrict__ WcT,
                         float* __restrict__ bcat) {
  int i = blockIdx.x * blockDim.x + threadIdx.x;
  if (i < 128 * 256) {                     // W1T [n][k]
    int n = i >> 8, k = i & 255;
    W1T[i] = __float2half(W1[k * 128 + n]);
  } else if (i < 2 * 128 * 256) {          // WcT [n][k]
    int j = i - 128 * 256;
    int n = j >> 7, k = j & 127;
    float f = (n < 128) ? Wmu[k * 128 + n] : Wls[k * 128 + (n - 128)];
    WcT[j] = __float2half(f);
  } else if (i < 2 * 128 * 256 + 256) {    // bcat
    int n = i - 2 * 128 * 256;
    bcat[n] = (n < 128) ? bmu[n] : bls[n - 128];
  }
}

// ---------------- MFMA GEMM (round-10 skeleton, 8 waves) — GEMM1 ----------------
// 512 thr = 8 waves (2 row x 4 col), wave tile 64x32, BM=128, BN=128, BK=32.
// Same barrier cadence, 2x resident waves for latency hiding.

#define LP 40  // LDS row stride in halves

__global__ __launch_bounds__(512) void k_gemm_mfma(
    const float* __restrict__ Av, const __half* __restrict__ WT,
    __half* __restrict__ out0, int M, int K) {
  __shared__ _Float16 As[128 * LP];
  __shared__ _Float16 Bs[128 * LP];

  const int tid = threadIdx.x;
  const int lane = tid & 63;
  const int wv = tid >> 6;                 // 0..7
  const int wr = wv >> 2, wc = wv & 3;     // 2 x 4 waves
  const int rsel = lane >> 4;
  const int rrow = lane & 15;
  const int row0 = blockIdx.x * 128;

  f32x4 acc[4][2];
#pragma unroll
  for (int m = 0; m < 4; m++)
#pragma unroll
    for (int n = 0; n < 2; n++) acc[m][n] = (f32x4){0.f, 0.f, 0.f, 0.f};

  const int srow = tid >> 2;               // 0..127
  const int skh = (tid & 3) * 8;           // 0,8,16,24

  for (int k0 = 0; k0 < K; k0 += 32) {
    if (row0 + srow < M) {
      const float* src = Av + (size_t)(row0 + srow) * K + k0 + skh;
      float4 f0 = *(const float4*)(src);
      float4 f1 = *(const float4*)(src + 4);
      f16x8 v0;
      v0[0]=(_Float16)f0.x; v0[1]=(_Float16)f0.y; v0[2]=(_Float16)f0.z; v0[3]=(_Float16)f0.w;
      v0[4]=(_Float16)f1.x; v0[5]=(_Float16)f1.y; v0[6]=(_Float16)f1.z; v0[7]=(_Float16)f1.w;
      *(f16x8*)&As[srow * LP + skh] = v0;
    } else {
      *(f16x8*)&As[srow * LP + skh] = (f16x8){0,0,0,0,0,0,0,0};
    }
    *(f16x8*)&Bs[srow * LP + skh] =
        *(const f16x8*)((const _Float16*)WT + (size_t)srow * K + k0 + skh);
    __syncthreads();

    f16x8 fa[4], fb[2];
#pragma unroll
    for (int m = 0; m < 4; m++)
      fa[m] = *(f16x8*)&As[(wr * 64 + m * 16 + rrow) * LP + rsel * 8];
#pragma unroll
    for (int n = 0; n < 2; n++)
      fb[n] = *(f16x8*)&Bs[(wc * 32 + n * 16 + rrow) * LP + rsel * 8];
#pragma unroll
    for (int m = 0; m < 4; m++)
#pragma unroll
      for (int n = 0; n < 2; n++)
        acc[m][n] = __builtin_amdgcn_mfma_f32_16x16x32_f16(fa[m], fb[n], acc[m][n], 0, 0, 0);
    __syncthreads();
  }

#pragma unroll
  for (int n = 0; n < 2; n++) {
    int c = wc * 32 + n * 16 + rrow;
#pragma unroll
    for (int m = 0; m < 4; m++) {
      f32x4 v = acc[m][n];
#pragma unroll
      for (int r = 0; r < 4; r++) {
        int row = row0 + wr * 64 + m * 16 + rsel * 4 + r;
        if (row < M) out0[(size_t)row * 128 + c] = __float2half(v[r]);
      }
    }
  }
}

// ---------------- pull-based SpMM (fp16 rows, on-the-fly norm) ----------------

__global__ __launch_bounds__(256) void k_spmm_h(
    const __half* __restrict__ in, const int* __restrict__ rowptr,
    const int* __restrict__ cnt, const int* __restrict__ col,
    const float* __restrict__ dinv,
    const float* __restrict__ bias, __half* __restrict__ out,
    int n, int use_bias, int relu_out) {
  int node = blockIdx.x * 4 + (threadIdx.x >> 6);
  if (node >= n) return;
  int lane = threadIdx.x & 63;

  const __half2* inp = (const __half2*)in;
  float di = dinv[node];
  float2 v = __half22float2(inp[(size_t)node * 64 + lane]);
  float accx = di * v.x;
  float accy = di * v.y;

  int beg = rowptr[node];
  int m = cnt[node];
  int i = 0;
  for (; i + 8 <= m; i += 8) {
    int c[8];
#pragma unroll
    for (int j = 0; j < 8; j++) c[j] = col[beg + i + j];
    float e[8];
#pragma unroll
    for (int j = 0; j < 8; j++) e[j] = dinv[c[j]];
    float2 u[8];
#pragma unroll
    for (int j = 0; j < 8; j++) u[j] = __half22float2(inp[(size_t)c[j] * 64 + lane]);
#pragma unroll
    for (int j = 0; j < 8; j++) { accx += e[j] * u[j].x; accy += e[j] * u[j].y; }
  }
  if (i < m) {
    int c[8];
#pragma unroll
    for (int j = 0; j < 8; j++) c[j] = col[(i + j < m) ? (beg + i + j) : beg];
    float e[8];
#pragma unroll
    for (int j = 0; j < 8; j++) e[j] = (i + j < m) ? dinv[c[j]] : 0.f;
    float2 u[8];
#pragma unroll
    for (int j = 0; j < 8; j++) u[j] = __half22float2(inp[(size_t)c[j] * 64 + lane]);
#pragma unroll
    for (int j = 0; j < 8; j++) { accx += e[j] * u[j].x; accy += e[j] * u[j].y; }
  }
  accx *= di;
  accy *= di;
  if (use_bias) {
    accx += bias[2 * lane];
    accy += bias[2 * lane + 1];
  }
  if (relu_out) {
    accx = fmaxf(accx, 0.f);
    accy = fmaxf(accy, 0.f);
  }
  ((__half2*)(out + (size_t)node * 128))[lane] = __floats2half2_rn(accx, accy);
}

// ---------------- fused SpMM2 + GEMM2 (round-14 structure, measured 113.8us) ----------------

__global__ __launch_bounds__(256) void k_spmm_gemm(
    const __half* __restrict__ in, const int* __restrict__ rowptr,
    const int* __restrict__ cnt, const int* __restrict__ col,
    const float* __restrict__ dinv,
    const __half* __restrict__ WcT, const float* __restrict__ bcat,
    float* __restrict__ out0, float* __restrict__ out1, int n) {
  __shared__ _Float16 gt[16 * 128];   // 16 rows x 256B, 16B-chunk XOR-swizzled by row
  const int tid = threadIdx.x;
  const int lane = tid & 63;
  const int w = tid >> 6;
  const __half2* inp = (const __half2*)in;

  for (int q = 0; q < 4; q++) {
    int li = w * 4 + q;
    int node = blockIdx.x * 16 + li;
    float accx = 0.f, accy = 0.f;
    if (node < n) {
      float di = dinv[node];
      float2 v = __half22float2(inp[(size_t)node * 64 + lane]);
      accx = di * v.x;
      accy = di * v.y;
      int beg = rowptr[node];
      int m = cnt[node];
      int i = 0;
      for (; i + 8 <= m; i += 8) {
        int c[8];
#pragma unroll
        for (int j = 0; j < 8; j++) c[j] = col[beg + i + j];
        float e[8];
#pragma unroll
        for (int j = 0; j < 8; j++) e[j] = dinv[c[j]];
        float2 u[8];
#pragma unroll
        for (int j = 0; j < 8; j++) u[j] = __half22float2(inp[(size_t)c[j] * 64 + lane]);
#pragma unroll
        for (int j = 0; j < 8; j++) { accx += e[j] * u[j].x; accy += e[j] * u[j].y; }
      }
      if (i < m) {
        int c[8];
#pragma unroll
        for (int j = 0; j < 8; j++) c[j] = col[(i + j < m) ? (beg + i + j) : beg];
        float e[8];
#pragma unroll
        for (int j = 0; j < 8; j++) e[j] = (i + j < m) ? dinv[c[j]] : 0.f;
        float2 u[8];
#pragma unroll
        for (int j = 0; j < 8; j++) u[j] = __half22float2(inp[(size_t)c[j] * 64 + lane]);
#pragma unroll
        for (int j = 0; j < 8; j++) { accx += e[j] * u[j].x; accy += e[j] * u[j].y; }
      }
      accx *= di;
      accy *= di;
    }
    int slot = (lane >> 2) ^ (li & 7);
    *(__half2*)((char*)gt + li * 256 + slot * 16 + (lane & 3) * 4) =
        __floats2half2_rn(accx, accy);
  }
  __syncthreads();

  const int lr = lane & 15;
  const int lk = lane >> 4;
  f16x8 a[4];
#pragma unroll
  for (int ks = 0; ks < 4; ks++) {
    int slot = (ks * 4 + lk) ^ (lr & 7);
    a[ks] = *(const f16x8*)((const char*)gt + lr * 256 + slot * 16);
  }
#pragma unroll
  for (int ct = 0; ct < 4; ct++) {
    int colg = (w * 4 + ct) * 16 + lr;    // 0..255
    f32x4 acc = (f32x4){0.f, 0.f, 0.f, 0.f};
#pragma unroll
    for (int ks = 0; ks < 4; ks++) {
      f16x8 b = *(const f16x8*)((const _Float16*)WcT + (size_t)colg * 128 + ks * 32 + lk * 8);
      acc = __builtin_amdgcn_mfma_f32_16x16x32_f16(a[ks], b, acc, 0, 0, 0);
    }
    float badd = bcat[colg];
    float* dst = out0;
    int c = colg;
    if (c >= 128) { dst = out1; c -= 128; }
#pragma unroll
    for (int r = 0; r < 4; r++) {
      int node = blockIdx.x * 16 + lk * 4 + r;
      if (node < n) dst[(size_t)node * 128 + c] = acc[r] + badd;
    }
  }
}

// ---------------- launch ----------------

extern "C" void kernel_launch(void* const* d_in, const int* in_sizes, int n_in,
                              void* d_out, int out_size, void* d_ws, size_t ws_size,
                              hipStream_t stream) {
  const float* x   = (const float*)d_in[0];
  const int*   ei  = (const int*)d_in[1];
  const float* W1  = (const float*)d_in[2];
  const float* b1  = (const float*)d_in[3];
  const float* Wmu = (const float*)d_in[4];
  const float* bmu = (const float*)d_in[5];
  const float* Wls = (const float*)d_in[6];
  const float* bls = (const float*)d_in[7];

  int N = in_sizes[0] / 256;
  int E = in_sizes[1] / 2;
  const int* src = ei;
  const int* dst = ei + E;

  int NBINS = (N + 127) >> 7;
  int NBLK  = (E + EPB - 1) / EPB;

  char* ws = (char*)d_ws;
  size_t o = 0;
  auto alloc = [&](size_t b) { size_t c = o; o = (o + b + 511) & ~(size_t)511; return c; };
  int*   cnt       = (int*)(ws + alloc((size_t)N * 4));
  int*   rowptr    = (int*)(ws + alloc((size_t)N * 4));
  float* dinv      = (float*)(ws + alloc((size_t)N * 4));
  int*   binCursor = (int*)(ws + alloc((size_t)NBINS * 4));
  int*   col       = (int*)(ws + alloc((size_t)NBINS * CAP * 4));
  int*   binned    = (int*)(ws + alloc((size_t)NBINS * CAP * 4));
  __half* W1T  = (__half*)(ws + alloc(128 * 256 * 2));
  __half* WcT  = (__half*)(ws + alloc(256 * 128 * 2));
  float*  bcat = (float*)(ws + alloc(256 * 4));
  __half* h0   = (__half*)(ws + alloc((size_t)N * 128 * 2));  // GEMM1 out
  __half* hBuf = (__half*)(ws + alloc((size_t)N * 128 * 2));  // h (relu'd)

  float* outMu = (float*)d_out;
  float* outLs = outMu + (size_t)N * 128;

  // ---- CSR build: reserve-scatter -> fused bin-finish ----
  hipMemsetAsync(binCursor, 0, (size_t)NBINS * 4, stream);
  k_fused_scatter<<<NBLK, 256, 0, stream>>>(src, dst, binCursor, binned, E, NBINS);
  k_bin_finish<<<NBINS, 256, 0, stream>>>(binned, binCursor, cnt, rowptr, dinv, col,
                                          NBINS, N);

  // ---- weights ----
  k_prep_w<<<(2 * 128 * 256 + 256 + 255) / 256, 256, 0, stream>>>(
      W1, Wmu, Wls, bmu, bls, W1T, WcT, bcat);

  // h0 = x @ W1                 [N,128] fp16 (8-wave round-10 skeleton)
  k_gemm_mfma<<<(N + 127) / 128, 512, 0, stream>>>(x, W1T, h0, N, 256);
  // h = relu(A h0 + b1)         [N,128] fp16
  k_spmm_h<<<(N + 3) / 4, 256, 0, stream>>>(h0, rowptr, cnt, col, dinv, b1, hBuf, N, 1, 1);
  // [mu|ls] = (A h) @ [Wmu|Wls] + [bmu|bls]   fused: g stays in LDS
  k_spmm_gemm<<<(N + 15) / 16, 256, 0, stream>>>(
      hBuf, rowptr, cnt, col, dinv, WcT, bcat, outMu, outLs, N);
}